// Round 3
// baseline (582.207 us; speedup 1.0000x reference)
//
#include <hip/hip_runtime.h>
#include <hip/hip_bf16.h>

#define D 128
#define SCAN_BLK 256
#define SCAN_VPT 4
#define SCAN_TILE (SCAN_BLK * SCAN_VPT)   // 1024 elements per scan block

typedef __attribute__((ext_vector_type(8))) short short8;   // 8 bf16 = 4 VGPR
typedef __attribute__((ext_vector_type(4))) float f32x4;    // MFMA C/D frag

// ---------------------------------------------------------------------------
// prep_w: WTl/WTr = bf16 transpose of Wl/Wr ([n][k] layout, 16B B-fragments);
// bsum = bl + br. Also zeroes the degree array (absorbs the memset dispatch).
// ---------------------------------------------------------------------------
__global__ __launch_bounds__(256) void prep_w(
    const float* __restrict__ Wl, const float* __restrict__ Wr,
    const float* __restrict__ bl, const float* __restrict__ br,
    __hip_bfloat16* __restrict__ WTl, __hip_bfloat16* __restrict__ WTr,
    float* __restrict__ bsum, int* __restrict__ deg, int n_nodes) {
  const int tid = blockIdx.x * 256 + threadIdx.x;  // grid 128 -> 0..32767
  const int n = (tid >> 7) & 127;
  const int k = tid & 127;
  if (tid < 16384) {
    WTl[n * D + k] = __float2bfloat16(Wl[k * D + n]);
  } else {
    WTr[n * D + k] = __float2bfloat16(Wr[k * D + n]);
  }
  if (tid < 128) bsum[tid] = bl[tid] + br[tid];
  for (int i = tid; i < n_nodes; i += 32768) deg[i] = 0;
}

// ---------------------------------------------------------------------------
// gemm_h: h = bf16(x @ Wl). Also absorbs the degree histogram as a
// grid-stride prologue (atomics overlap with other waves' MFMA).
// ---------------------------------------------------------------------------
__global__ __launch_bounds__(256) void gemm_h(
    const float* __restrict__ x, const __hip_bfloat16* __restrict__ WTl,
    __hip_bfloat16* __restrict__ h,
    const int* __restrict__ edst, int* __restrict__ deg, int n_edges,
    int n_rowtiles) {
  const int gsz = gridDim.x * 256;
  for (int e = blockIdx.x * 256 + threadIdx.x; e < n_edges; e += gsz)
    atomicAdd(&deg[edst[e]], 1);

  __shared__ __hip_bfloat16 xs[16][136];   // +8 pad
  const int t = threadIdx.x;
  const int wave = t >> 6;
  const int lane = t & 63;
  const int m = lane & 15;
  const int q = lane >> 4;

  short8 bfrag[2][4];
#pragma unroll
  for (int c = 0; c < 2; ++c) {
    const int n0 = wave * 32 + c * 16;
#pragma unroll
    for (int ks = 0; ks < 4; ++ks)
      bfrag[c][ks] = *(const short8*)&WTl[(n0 + m) * D + ks * 32 + q * 8];
  }

  const int srow = t >> 4;
  const int scol = (t & 15) * 8;

  for (int rt = blockIdx.x; rt < n_rowtiles; rt += gridDim.x) {
    const int rowbase = rt * 16;
    {
      const float4* src = (const float4*)&x[(size_t)(rowbase + srow) * D + scol];
      const float4 v0 = src[0], v1 = src[1];
      __hip_bfloat16* dst = &xs[srow][scol];
      dst[0] = __float2bfloat16(v0.x); dst[1] = __float2bfloat16(v0.y);
      dst[2] = __float2bfloat16(v0.z); dst[3] = __float2bfloat16(v0.w);
      dst[4] = __float2bfloat16(v1.x); dst[5] = __float2bfloat16(v1.y);
      dst[6] = __float2bfloat16(v1.z); dst[7] = __float2bfloat16(v1.w);
    }
    __syncthreads();

    f32x4 acc[2];
#pragma unroll
    for (int c = 0; c < 2; ++c)
#pragma unroll
      for (int r = 0; r < 4; ++r) acc[c][r] = 0.f;

#pragma unroll
    for (int ks = 0; ks < 4; ++ks) {
      const short8 afrag = *(const short8*)&xs[m][ks * 32 + q * 8];
#pragma unroll
      for (int c = 0; c < 2; ++c)
        acc[c] = __builtin_amdgcn_mfma_f32_16x16x32_bf16(afrag, bfrag[c][ks], acc[c], 0, 0, 0);
    }

#pragma unroll
    for (int c = 0; c < 2; ++c) {
      const int n = wave * 32 + c * 16 + m;
#pragma unroll
      for (int r = 0; r < 4; ++r)
        h[(size_t)(rowbase + q * 4 + r) * D + n] = __float2bfloat16(acc[c][r]);
    }
    __syncthreads();
  }
}

// ---------------------------------------------------------------------------
// scan1: block-level exclusive scan of deg -> offsets + per-block totals.
// ---------------------------------------------------------------------------
__global__ __launch_bounds__(SCAN_BLK) void scan1_kernel(
    const int* __restrict__ deg, int* __restrict__ offsets,
    int* __restrict__ partials, int n) {
  __shared__ int sdata[SCAN_BLK];
  const int t = threadIdx.x;
  const int base = blockIdx.x * SCAN_TILE + t * SCAN_VPT;

  int v[SCAN_VPT];
  int s = 0;
#pragma unroll
  for (int j = 0; j < SCAN_VPT; ++j) {
    v[j] = (base + j < n) ? deg[base + j] : 0;
    s += v[j];
  }
  sdata[t] = s;
  __syncthreads();
  for (int off = 1; off < SCAN_BLK; off <<= 1) {
    int xv = (t >= off) ? sdata[t - off] : 0;
    __syncthreads();
    sdata[t] += xv;
    __syncthreads();
  }
  int excl = sdata[t] - s;
  if (t == SCAN_BLK - 1) partials[blockIdx.x] = sdata[t];
  int run = excl;
#pragma unroll
  for (int j = 0; j < SCAN_VPT; ++j) {
    if (base + j < n) offsets[base + j] = run;
    run += v[j];
  }
}

// ---------------------------------------------------------------------------
// scan3: adds block-prefix (scan2 folded in), materializes pos[] cursors.
// ---------------------------------------------------------------------------
__global__ __launch_bounds__(SCAN_BLK) void scan3_kernel(
    int* __restrict__ offsets, int* __restrict__ pos,
    const int* __restrict__ partials, int n, int n_edges) {
  __shared__ int s_add;
  const int t = threadIdx.x;
  if (t < 64) {
    int v = 0;
    for (int j = t; j < blockIdx.x; j += 64) v += partials[j];
#pragma unroll
    for (int off = 32; off > 0; off >>= 1) v += __shfl_down(v, off);
    if (t == 0) s_add = v;
  }
  __syncthreads();
  const int add = s_add;
  const int base = blockIdx.x * SCAN_TILE + t * SCAN_VPT;
#pragma unroll
  for (int j = 0; j < SCAN_VPT; ++j) {
    const int i = base + j;
    if (i < n) {
      const int o = offsets[i] + add;
      offsets[i] = o;
      pos[i] = o;
    }
  }
  if (blockIdx.x == 0 && t == 0) offsets[n] = n_edges;
}

// ---------------------------------------------------------------------------
// scatter: pairs[slot] = {src | (dst_local<<24), bits(weight)} dst-sorted.
// dst_local = dst & 15 (tiles are aligned 16-node groups); src < 2^24.
// ---------------------------------------------------------------------------
__global__ __launch_bounds__(256) void scatter_kernel(
    const int* __restrict__ esrc, const int* __restrict__ edst,
    const float* __restrict__ ew, int* __restrict__ pos,
    int2* __restrict__ pairs, int n_edges) {
  const int e = blockIdx.x * 256 + threadIdx.x;
  if (e >= n_edges) return;
  const int d = edst[e];
  const int slot = atomicAdd(&pos[d], 1);
  pairs[slot] = make_int2(esrc[e] | ((d & 15) << 24), __float_as_int(ew[e]));
}

// ---------------------------------------------------------------------------
// sage_out v4: fused root-GEMM + EDGE-PARALLEL aggregation via LDS f32 atomics.
//   phase 1: MFMA x @ Wr + bsum -> ot (parity-swizzled cols)
//   phase 2: each wave takes a contiguous quarter of the tile's edges;
//            8-edge batches: 8 uniform pair loads, 8 independent 4B/lane
//            gathers of h (MLP, no dependent chain, no staging), then
//            ds_add_f32 into ot. Col swizzle slot=(c&1)*64+c/2 makes both
//            atomics 2-way-bank (free).
//   LDS 12.5 KB -> wave-capped ~6-8 blocks/CU; balanced per-wave edge split.
// ---------------------------------------------------------------------------
__global__ __launch_bounds__(256) void sage_out(
    const float* __restrict__ x, const __hip_bfloat16* __restrict__ WTr,
    const float* __restrict__ bsum, const __hip_bfloat16* __restrict__ h,
    const int* __restrict__ offsets, const int2* __restrict__ pairs,
    float* __restrict__ out) {
  __shared__ float ot[16][D];              // 8 KB, cols parity-swizzled
  __shared__ __hip_bfloat16 xs[16][136];   // 4.25 KB
  const int t = threadIdx.x;
  const int wave = t >> 6;
  const int lane = t & 63;
  const int m = lane & 15;
  const int q = lane >> 4;
  const int rowbase = blockIdx.x * 16;

  // edge range for this tile + this wave's contiguous quarter
  const int gB0 = offsets[rowbase];
  const int Eb = offsets[rowbase + 16] - gB0;
  int wb = gB0 + ((Eb * wave) >> 2);
  int we = gB0 + ((Eb * (wave + 1)) >> 2);
  wb = __builtin_amdgcn_readfirstlane(wb);
  we = __builtin_amdgcn_readfirstlane(we);

  // ---- phase 1: root GEMM ----
  short8 bfrag[2][4];
#pragma unroll
  for (int c = 0; c < 2; ++c) {
    const int n0 = wave * 32 + c * 16;
#pragma unroll
    for (int ks = 0; ks < 4; ++ks)
      bfrag[c][ks] = *(const short8*)&WTr[(n0 + m) * D + ks * 32 + q * 8];
  }

  {
    const int srow = t >> 4;
    const int scol = (t & 15) * 8;
    const float4* src = (const float4*)&x[(size_t)(rowbase + srow) * D + scol];
    const float4 v0 = src[0], v1 = src[1];
    __hip_bfloat16* dst = &xs[srow][scol];
    dst[0] = __float2bfloat16(v0.x); dst[1] = __float2bfloat16(v0.y);
    dst[2] = __float2bfloat16(v0.z); dst[3] = __float2bfloat16(v0.w);
    dst[4] = __float2bfloat16(v1.x); dst[5] = __float2bfloat16(v1.y);
    dst[6] = __float2bfloat16(v1.z); dst[7] = __float2bfloat16(v1.w);
  }
  __syncthreads();

  f32x4 acc[2];
#pragma unroll
  for (int c = 0; c < 2; ++c)
#pragma unroll
    for (int r = 0; r < 4; ++r) acc[c][r] = 0.f;

#pragma unroll
  for (int ks = 0; ks < 4; ++ks) {
    const short8 afrag = *(const short8*)&xs[m][ks * 32 + q * 8];
#pragma unroll
    for (int c = 0; c < 2; ++c)
      acc[c] = __builtin_amdgcn_mfma_f32_16x16x32_bf16(afrag, bfrag[c][ks], acc[c], 0, 0, 0);
  }

  // ot write, parity-swizzled: col n -> slot (n&1)*64 + n/2
#pragma unroll
  for (int c = 0; c < 2; ++c) {
    const int n = wave * 32 + c * 16 + m;
    const float b = bsum[n];
    const int slot = ((n & 1) << 6) | (n >> 1);
#pragma unroll
    for (int r = 0; r < 4; ++r)
      ot[q * 4 + r][slot] = acc[c][r] + b;
  }
  __syncthreads();   // ot initialized -> atomics may begin

  // ---- phase 2: edge-parallel aggregation ----
  // lane covers cols {2*lane, 2*lane+1} = swizzled slots {lane, 64+lane}
  const __hip_bfloat162* __restrict__ h2 = (const __hip_bfloat162*)h;
  float* __restrict__ otf = &ot[0][0];

  int i = wb;
  for (; i + 8 <= we; i += 8) {
    int2 pr[8];
#pragma unroll
    for (int j = 0; j < 8; ++j) pr[j] = pairs[i + j];
    __hip_bfloat162 hv[8];
#pragma unroll
    for (int j = 0; j < 8; ++j)
      hv[j] = h2[(size_t)(pr[j].x & 0x00FFFFFF) * (D / 2) + lane];
#pragma unroll
    for (int j = 0; j < 8; ++j) {
      const float w = __int_as_float(pr[j].y);
      const int dl = ((unsigned)pr[j].x) >> 24;
      atomicAdd(&otf[dl * D + lane], w * __bfloat162float(hv[j].x));
      atomicAdd(&otf[dl * D + 64 + lane], w * __bfloat162float(hv[j].y));
    }
  }
  for (; i < we; ++i) {
    const int2 pr = pairs[i];
    const __hip_bfloat162 hvs = h2[(size_t)(pr.x & 0x00FFFFFF) * (D / 2) + lane];
    const float w = __int_as_float(pr.y);
    const int dl = ((unsigned)pr.x) >> 24;
    atomicAdd(&otf[dl * D + lane], w * __bfloat162float(hvs.x));
    atomicAdd(&otf[dl * D + 64 + lane], w * __bfloat162float(hvs.y));
  }
  __syncthreads();   // all atomics done

  // epilogue: unswizzle + store. wave owns rows wave*4..+3.
#pragma unroll
  for (int j = 0; j < 4; ++j) {
    const int ln = wave * 4 + j;
    float2 o;
    o.x = ot[ln][lane];        // col 2*lane
    o.y = ot[ln][64 + lane];   // col 2*lane+1
    *(float2*)&out[(size_t)(rowbase + ln) * D + 2 * lane] = o;
  }
}

// ---------------------------------------------------------------------------
extern "C" void kernel_launch(void* const* d_in, const int* in_sizes, int n_in,
                              void* d_out, int out_size, void* d_ws, size_t ws_size,
                              hipStream_t stream) {
  const float* x   = (const float*)d_in[0];
  const int* esrc  = (const int*)d_in[1];
  const int* edst  = (const int*)d_in[2];
  const float* ew  = (const float*)d_in[3];
  const float* Wl  = (const float*)d_in[4];
  const float* bl  = (const float*)d_in[5];
  const float* Wr  = (const float*)d_in[6];
  const float* br  = (const float*)d_in[7];
  float* out = (float*)d_out;

  const int n_nodes = in_sizes[0] / D;   // 100000
  const int n_edges = in_sizes[1];       // 600000

  // Workspace layout (16B aligned sections)
  char* ws = (char*)d_ws;
  size_t off = 0;
  __hip_bfloat16* h = (__hip_bfloat16*)(ws + off);      // 25.6 MB
  off += (size_t)n_nodes * D * sizeof(__hip_bfloat16);
  off = (off + 15) & ~15ull;
  int* offsets = (int*)(ws + off);
  off += (size_t)(n_nodes + 1) * sizeof(int);
  off = (off + 15) & ~15ull;
  int* pos = (int*)(ws + off);                          // degree, then cursors
  off += (size_t)n_nodes * sizeof(int);
  off = (off + 15) & ~15ull;
  int* partials = (int*)(ws + off);
  off += 1024 * sizeof(int);
  off = (off + 15) & ~15ull;
  int2* pairs = (int2*)(ws + off);                      // 4.8 MB
  off += (size_t)n_edges * sizeof(int2);
  off = (off + 15) & ~15ull;
  __hip_bfloat16* WTl = (__hip_bfloat16*)(ws + off);
  off += (size_t)D * D * sizeof(__hip_bfloat16);
  __hip_bfloat16* WTr = (__hip_bfloat16*)(ws + off);
  off += (size_t)D * D * sizeof(__hip_bfloat16);
  float* bsum = (float*)(ws + off);
  off += D * sizeof(float);

  const int n_rowtiles = (n_nodes + 15) / 16;           // 6250 (exact)

  prep_w<<<128, 256, 0, stream>>>(Wl, Wr, bl, br, WTl, WTr, bsum, pos, n_nodes);

  const int gemm_grid = n_rowtiles < 2048 ? n_rowtiles : 2048;
  gemm_h<<<gemm_grid, 256, 0, stream>>>(x, WTl, h, edst, pos, n_edges, n_rowtiles);

  const int nparts = (n_nodes + SCAN_TILE - 1) / SCAN_TILE;   // 98
  scan1_kernel<<<nparts, SCAN_BLK, 0, stream>>>(pos, offsets, partials, n_nodes);
  scan3_kernel<<<nparts, SCAN_BLK, 0, stream>>>(offsets, pos, partials, n_nodes, n_edges);
  scatter_kernel<<<(n_edges + 255) / 256, 256, 0, stream>>>(esrc, edst, ew, pos, pairs, n_edges);

  sage_out<<<n_rowtiles, 256, 0, stream>>>(x, WTr, bsum, h, offsets, pairs, out);
}

// Round 4
// 538.575 us; speedup vs baseline: 1.0810x; 1.0810x over previous
//
#include <hip/hip_runtime.h>
#include <hip/hip_bf16.h>
#include <hip/hip_cooperative_groups.h>

namespace cg = cooperative_groups;

#define D 128
#define CS_BLOCKS 1024
#define CS_CHUNK 128   // nodes per coop_sort block; 1024*128 = 131072 >= n_nodes

typedef __attribute__((ext_vector_type(8))) short short8;   // 8 bf16 = 4 VGPR
typedef __attribute__((ext_vector_type(4))) float f32x4;    // MFMA C/D frag

// ---------------------------------------------------------------------------
// prep_w: WTl/WTr = bf16 transpose of Wl/Wr ([n][k] layout, 16B B-fragments);
// bsum = bl + br. Also zeroes the degree array (absorbs the memset dispatch).
// ---------------------------------------------------------------------------
__global__ __launch_bounds__(256) void prep_w(
    const float* __restrict__ Wl, const float* __restrict__ Wr,
    const float* __restrict__ bl, const float* __restrict__ br,
    __hip_bfloat16* __restrict__ WTl, __hip_bfloat16* __restrict__ WTr,
    float* __restrict__ bsum, int* __restrict__ deg, int n_nodes) {
  const int tid = blockIdx.x * 256 + threadIdx.x;  // grid 128 -> 0..32767
  const int n = (tid >> 7) & 127;
  const int k = tid & 127;
  if (tid < 16384) {
    WTl[n * D + k] = __float2bfloat16(Wl[k * D + n]);
  } else {
    WTr[n * D + k] = __float2bfloat16(Wr[k * D + n]);
  }
  if (tid < 128) bsum[tid] = bl[tid] + br[tid];
  for (int i = tid; i < n_nodes; i += 32768) deg[i] = 0;
}

// ---------------------------------------------------------------------------
// gemm_h: h = bf16(x @ Wl). Also absorbs the degree histogram as a
// grid-stride prologue (atomics overlap with other waves' MFMA).
// ---------------------------------------------------------------------------
__global__ __launch_bounds__(256) void gemm_h(
    const float* __restrict__ x, const __hip_bfloat16* __restrict__ WTl,
    __hip_bfloat16* __restrict__ h,
    const int* __restrict__ edst, int* __restrict__ deg, int n_edges,
    int n_rowtiles) {
  const int gsz = gridDim.x * 256;
  for (int e = blockIdx.x * 256 + threadIdx.x; e < n_edges; e += gsz)
    atomicAdd(&deg[edst[e]], 1);

  __shared__ __hip_bfloat16 xs[16][136];   // +8 pad
  const int t = threadIdx.x;
  const int wave = t >> 6;
  const int lane = t & 63;
  const int m = lane & 15;
  const int q = lane >> 4;

  short8 bfrag[2][4];
#pragma unroll
  for (int c = 0; c < 2; ++c) {
    const int n0 = wave * 32 + c * 16;
#pragma unroll
    for (int ks = 0; ks < 4; ++ks)
      bfrag[c][ks] = *(const short8*)&WTl[(n0 + m) * D + ks * 32 + q * 8];
  }

  const int srow = t >> 4;
  const int scol = (t & 15) * 8;

  for (int rt = blockIdx.x; rt < n_rowtiles; rt += gridDim.x) {
    const int rowbase = rt * 16;
    {
      const float4* src = (const float4*)&x[(size_t)(rowbase + srow) * D + scol];
      const float4 v0 = src[0], v1 = src[1];
      __hip_bfloat16* dst = &xs[srow][scol];
      dst[0] = __float2bfloat16(v0.x); dst[1] = __float2bfloat16(v0.y);
      dst[2] = __float2bfloat16(v0.z); dst[3] = __float2bfloat16(v0.w);
      dst[4] = __float2bfloat16(v1.x); dst[5] = __float2bfloat16(v1.y);
      dst[6] = __float2bfloat16(v1.z); dst[7] = __float2bfloat16(v1.w);
    }
    __syncthreads();

    f32x4 acc[2];
#pragma unroll
    for (int c = 0; c < 2; ++c)
#pragma unroll
      for (int r = 0; r < 4; ++r) acc[c][r] = 0.f;

#pragma unroll
    for (int ks = 0; ks < 4; ++ks) {
      const short8 afrag = *(const short8*)&xs[m][ks * 32 + q * 8];
#pragma unroll
      for (int c = 0; c < 2; ++c)
        acc[c] = __builtin_amdgcn_mfma_f32_16x16x32_bf16(afrag, bfrag[c][ks], acc[c], 0, 0, 0);
    }

#pragma unroll
    for (int c = 0; c < 2; ++c) {
      const int n = wave * 32 + c * 16 + m;
#pragma unroll
      for (int r = 0; r < 4; ++r)
        h[(size_t)(rowbase + q * 4 + r) * D + n] = __float2bfloat16(acc[c][r]);
    }
    __syncthreads();
  }
}

// ---------------------------------------------------------------------------
// coop_sort: scan1 + scan3 + scatter fused via cooperative grid sync.
//   phase 1: per-block exclusive scan of a 128-node chunk of deg
//   phase 2: block prefix from partials (wave 0), write offsets + pos cursors
//   phase 3: grid-stride scatter: pairs[slot] = {src, bits(w)} dst-sorted
// ---------------------------------------------------------------------------
__global__ __launch_bounds__(256) void coop_sort(
    int* __restrict__ pos /* deg in, cursors out */, int* __restrict__ offsets,
    int* __restrict__ partials,
    const int* __restrict__ esrc, const int* __restrict__ edst,
    const float* __restrict__ ew, int2* __restrict__ pairs,
    int n, int n_edges) {
  cg::grid_group grid = cg::this_grid();
  __shared__ int sdata[256];
  __shared__ int s_add;
  const int t = threadIdx.x;
  const int b = blockIdx.x;
  const int base = b * CS_CHUNK;
  const bool act = (t < CS_CHUNK) && (base + t < n);

  // phase 1: block-local scan
  int v = act ? pos[base + t] : 0;
  sdata[t] = v;
  __syncthreads();
  for (int off = 1; off < 256; off <<= 1) {
    int xv = (t >= off) ? sdata[t - off] : 0;
    __syncthreads();
    sdata[t] += xv;
    __syncthreads();
  }
  const int excl = sdata[t] - v;
  if (t == 255) partials[b] = sdata[t];
  if (act) offsets[base + t] = excl;

  __threadfence();
  grid.sync();

  // phase 2: add block prefix, materialize offsets + pos cursors
  if (t < 64) {
    int s = 0;
    for (int j = t; j < b; j += 64) s += partials[j];
#pragma unroll
    for (int off = 32; off > 0; off >>= 1) s += __shfl_down(s, off);
    if (t == 0) s_add = s;
  }
  __syncthreads();
  const int add = s_add;
  if (act) {
    const int o = offsets[base + t] + add;
    offsets[base + t] = o;
    pos[base + t] = o;
  }
  if (b == 0 && t == 0) offsets[n] = n_edges;

  __threadfence();
  grid.sync();

  // phase 3: scatter
  const int gsz = gridDim.x * 256;
  for (int e = b * 256 + t; e < n_edges; e += gsz) {
    const int d = edst[e];
    const int slot = atomicAdd(&pos[d], 1);
    pairs[slot] = make_int2(esrc[e], __float_as_int(ew[e]));
  }
}

// ---------------------------------------------------------------------------
// sage_out v5: v1 structure (best measured) with 8-edge unrolled batches.
//   phase 1: MFMA x @ Wr + bsum -> LDS tile ot[16][128]
//   phase 2: each wave aggregates 4 nodes' edges; 8 independent gathers in
//            flight per batch (double v1's MLP), register accumulation,
//            writes out ONCE.
// ---------------------------------------------------------------------------
__global__ __launch_bounds__(256) void sage_out(
    const float* __restrict__ x, const __hip_bfloat16* __restrict__ WTr,
    const float* __restrict__ bsum, const __hip_bfloat16* __restrict__ h,
    const int* __restrict__ offsets, const int2* __restrict__ pairs,
    float* __restrict__ out) {
  __shared__ __hip_bfloat16 xs[16][136];
  __shared__ float ot[16][D];
  const int t = threadIdx.x;
  const int wave = t >> 6;
  const int lane = t & 63;
  const int m = lane & 15;
  const int q = lane >> 4;
  const int rowbase = blockIdx.x * 16;

  // B fragments: Wr cols wave*32 .. +31
  short8 bfrag[2][4];
#pragma unroll
  for (int c = 0; c < 2; ++c) {
    const int n0 = wave * 32 + c * 16;
#pragma unroll
    for (int ks = 0; ks < 4; ++ks)
      bfrag[c][ks] = *(const short8*)&WTr[(n0 + m) * D + ks * 32 + q * 8];
  }

  // stage x tile fp32 -> bf16
  {
    const int srow = t >> 4;
    const int scol = (t & 15) * 8;
    const float4* src = (const float4*)&x[(size_t)(rowbase + srow) * D + scol];
    const float4 v0 = src[0], v1 = src[1];
    __hip_bfloat16* dst = &xs[srow][scol];
    dst[0] = __float2bfloat16(v0.x); dst[1] = __float2bfloat16(v0.y);
    dst[2] = __float2bfloat16(v0.z); dst[3] = __float2bfloat16(v0.w);
    dst[4] = __float2bfloat16(v1.x); dst[5] = __float2bfloat16(v1.y);
    dst[6] = __float2bfloat16(v1.z); dst[7] = __float2bfloat16(v1.w);
  }
  __syncthreads();

  f32x4 acc[2];
#pragma unroll
  for (int c = 0; c < 2; ++c)
#pragma unroll
    for (int r = 0; r < 4; ++r) acc[c][r] = 0.f;

#pragma unroll
  for (int ks = 0; ks < 4; ++ks) {
    const short8 afrag = *(const short8*)&xs[m][ks * 32 + q * 8];
#pragma unroll
    for (int c = 0; c < 2; ++c)
      acc[c] = __builtin_amdgcn_mfma_f32_16x16x32_bf16(afrag, bfrag[c][ks], acc[c], 0, 0, 0);
  }

#pragma unroll
  for (int c = 0; c < 2; ++c) {
    const int n = wave * 32 + c * 16 + m;
    const float b = bsum[n];
#pragma unroll
    for (int r = 0; r < 4; ++r)
      ot[q * 4 + r][n] = acc[c][r] + b;
  }
  __syncthreads();

  // phase 2: wave handles nodes rowbase + wave*4 + 0..3
  const __hip_bfloat162* __restrict__ h2 = (const __hip_bfloat162*)h;
#pragma unroll
  for (int j = 0; j < 4; ++j) {
    const int ln = wave * 4 + j;
    const int node = rowbase + ln;
    const int begin = offsets[node];
    const int end = offsets[node + 1];

    float2 a = *(const float2*)&ot[ln][2 * lane];

    int i = begin;
    for (; i + 8 <= end; i += 8) {
      int2 p[8];
#pragma unroll
      for (int u = 0; u < 8; ++u) p[u] = pairs[i + u];
      __hip_bfloat162 hv[8];
#pragma unroll
      for (int u = 0; u < 8; ++u)
        hv[u] = h2[(size_t)p[u].x * (D / 2) + lane];
#pragma unroll
      for (int u = 0; u < 8; ++u) {
        const float w = __int_as_float(p[u].y);
        a.x = fmaf(w, __bfloat162float(hv[u].x), a.x);
        a.y = fmaf(w, __bfloat162float(hv[u].y), a.y);
      }
    }
    for (; i + 4 <= end; i += 4) {
      const int2 p0 = pairs[i + 0];
      const int2 p1 = pairs[i + 1];
      const int2 p2 = pairs[i + 2];
      const int2 p3 = pairs[i + 3];
      const __hip_bfloat162 a0 = h2[(size_t)p0.x * (D / 2) + lane];
      const __hip_bfloat162 a1 = h2[(size_t)p1.x * (D / 2) + lane];
      const __hip_bfloat162 a2 = h2[(size_t)p2.x * (D / 2) + lane];
      const __hip_bfloat162 a3 = h2[(size_t)p3.x * (D / 2) + lane];
      const float w0 = __int_as_float(p0.y), w1 = __int_as_float(p1.y);
      const float w2 = __int_as_float(p2.y), w3 = __int_as_float(p3.y);
      a.x = fmaf(w0, __bfloat162float(a0.x), a.x);
      a.y = fmaf(w0, __bfloat162float(a0.y), a.y);
      a.x = fmaf(w1, __bfloat162float(a1.x), a.x);
      a.y = fmaf(w1, __bfloat162float(a1.y), a.y);
      a.x = fmaf(w2, __bfloat162float(a2.x), a.x);
      a.y = fmaf(w2, __bfloat162float(a2.y), a.y);
      a.x = fmaf(w3, __bfloat162float(a3.x), a.x);
      a.y = fmaf(w3, __bfloat162float(a3.y), a.y);
    }
    for (; i < end; ++i) {
      const int2 p = pairs[i];
      const __hip_bfloat162 av = h2[(size_t)p.x * (D / 2) + lane];
      const float w = __int_as_float(p.y);
      a.x = fmaf(w, __bfloat162float(av.x), a.x);
      a.y = fmaf(w, __bfloat162float(av.y), a.y);
    }
    *(float2*)&out[(size_t)node * D + 2 * lane] = a;
  }
}

// ---------------------------------------------------------------------------
extern "C" void kernel_launch(void* const* d_in, const int* in_sizes, int n_in,
                              void* d_out, int out_size, void* d_ws, size_t ws_size,
                              hipStream_t stream) {
  const float* x   = (const float*)d_in[0];
  const int* esrc  = (const int*)d_in[1];
  const int* edst  = (const int*)d_in[2];
  const float* ew  = (const float*)d_in[3];
  const float* Wl  = (const float*)d_in[4];
  const float* bl  = (const float*)d_in[5];
  const float* Wr  = (const float*)d_in[6];
  const float* br  = (const float*)d_in[7];
  float* out = (float*)d_out;

  const int n_nodes = in_sizes[0] / D;   // 100000
  const int n_edges = in_sizes[1];       // 600000

  // Workspace layout (16B aligned sections)
  char* ws = (char*)d_ws;
  size_t off = 0;
  __hip_bfloat16* h = (__hip_bfloat16*)(ws + off);      // 25.6 MB
  off += (size_t)n_nodes * D * sizeof(__hip_bfloat16);
  off = (off + 15) & ~15ull;
  int* offsets = (int*)(ws + off);
  off += (size_t)(n_nodes + 1) * sizeof(int);
  off = (off + 15) & ~15ull;
  int* pos = (int*)(ws + off);                          // degree, then cursors
  off += (size_t)n_nodes * sizeof(int);
  off = (off + 15) & ~15ull;
  int* partials = (int*)(ws + off);
  off += 1024 * sizeof(int);
  off = (off + 15) & ~15ull;
  int2* pairs = (int2*)(ws + off);                      // 4.8 MB
  off += (size_t)n_edges * sizeof(int2);
  off = (off + 15) & ~15ull;
  __hip_bfloat16* WTl = (__hip_bfloat16*)(ws + off);
  off += (size_t)D * D * sizeof(__hip_bfloat16);
  __hip_bfloat16* WTr = (__hip_bfloat16*)(ws + off);
  off += (size_t)D * D * sizeof(__hip_bfloat16);
  float* bsum = (float*)(ws + off);
  off += D * sizeof(float);

  const int n_rowtiles = (n_nodes + 15) / 16;           // 6250 (exact)

  prep_w<<<128, 256, 0, stream>>>(Wl, Wr, bl, br, WTl, WTr, bsum, pos, n_nodes);

  const int gemm_grid = n_rowtiles < 2048 ? n_rowtiles : 2048;
  gemm_h<<<gemm_grid, 256, 0, stream>>>(x, WTl, h, edst, pos, n_edges, n_rowtiles);

  // fused scan + scatter (cooperative)
  {
    int nn = n_nodes, ne = n_edges;
    void* args[] = {(void*)&pos,  (void*)&offsets, (void*)&partials,
                    (void*)&esrc, (void*)&edst,    (void*)&ew,
                    (void*)&pairs, (void*)&nn,     (void*)&ne};
    hipLaunchCooperativeKernel((void*)coop_sort, dim3(CS_BLOCKS), dim3(256),
                               args, 0, stream);
  }

  sage_out<<<n_rowtiles, 256, 0, stream>>>(x, WTr, bsum, h, offsets, pairs, out);
}

// Round 6
// 236.674 us; speedup vs baseline: 2.4599x; 2.2756x over previous
//
#include <hip/hip_runtime.h>
#include <hip/hip_bf16.h>

#define D 128
#define SCAN_BLK 256
#define SCAN_VPT 4
#define SCAN_TILE (SCAN_BLK * SCAN_VPT)   // 1024 elements per scan block

typedef __attribute__((ext_vector_type(8))) short short8;   // 8 bf16 = 4 VGPR
typedef __attribute__((ext_vector_type(4))) float f32x4;    // MFMA C/D frag

// ---------------------------------------------------------------------------
// prep_w: WTl/WTr = bf16 transpose of Wl/Wr ([n][k] layout, 16B B-fragments);
// bsum = bl + br. Also zeroes the degree array (absorbs the memset dispatch).
// ---------------------------------------------------------------------------
__global__ __launch_bounds__(256) void prep_w(
    const float* __restrict__ Wl, const float* __restrict__ Wr,
    const float* __restrict__ bl, const float* __restrict__ br,
    __hip_bfloat16* __restrict__ WTl, __hip_bfloat16* __restrict__ WTr,
    float* __restrict__ bsum, int* __restrict__ deg, int n_nodes) {
  const int tid = blockIdx.x * 256 + threadIdx.x;  // grid 128 -> 0..32767
  const int n = (tid >> 7) & 127;
  const int k = tid & 127;
  if (tid < 16384) {
    WTl[n * D + k] = __float2bfloat16(Wl[k * D + n]);
  } else {
    WTr[n * D + k] = __float2bfloat16(Wr[k * D + n]);
  }
  if (tid < 128) bsum[tid] = bl[tid] + br[tid];
  for (int i = tid; i < n_nodes; i += 32768) deg[i] = 0;
}

// ---------------------------------------------------------------------------
// gemm_hr: h = bf16(x @ Wl) -> ws  AND  out = x @ Wr + bsum (fp32, the root
// branch). x tile staged once, 16 MFMAs per tile. Histogram prologue kept
// (atomics overlap other waves' MFMA).
// ---------------------------------------------------------------------------
__global__ __launch_bounds__(256) void gemm_hr(
    const float* __restrict__ x, const __hip_bfloat16* __restrict__ WTl,
    const __hip_bfloat16* __restrict__ WTr, const float* __restrict__ bsum,
    __hip_bfloat16* __restrict__ h, float* __restrict__ out,
    const int* __restrict__ edst, int* __restrict__ deg, int n_edges,
    int n_rowtiles) {
  // histogram prologue
  const int gsz = gridDim.x * 256;
  for (int e = blockIdx.x * 256 + threadIdx.x; e < n_edges; e += gsz)
    atomicAdd(&deg[edst[e]], 1);

  __shared__ __hip_bfloat16 xs[16][136];   // +8 pad
  const int t = threadIdx.x;
  const int wave = t >> 6;
  const int lane = t & 63;
  const int m = lane & 15;
  const int q = lane >> 4;

  short8 bfl[2][4], bfr[2][4];
  float bias[2];
#pragma unroll
  for (int c = 0; c < 2; ++c) {
    const int n0 = wave * 32 + c * 16;
    bias[c] = bsum[n0 + m];
#pragma unroll
    for (int ks = 0; ks < 4; ++ks) {
      bfl[c][ks] = *(const short8*)&WTl[(n0 + m) * D + ks * 32 + q * 8];
      bfr[c][ks] = *(const short8*)&WTr[(n0 + m) * D + ks * 32 + q * 8];
    }
  }

  const int srow = t >> 4;
  const int scol = (t & 15) * 8;

  for (int rt = blockIdx.x; rt < n_rowtiles; rt += gridDim.x) {
    const int rowbase = rt * 16;
    {
      const float4* src = (const float4*)&x[(size_t)(rowbase + srow) * D + scol];
      const float4 v0 = src[0], v1 = src[1];
      __hip_bfloat16* dst = &xs[srow][scol];
      dst[0] = __float2bfloat16(v0.x); dst[1] = __float2bfloat16(v0.y);
      dst[2] = __float2bfloat16(v0.z); dst[3] = __float2bfloat16(v0.w);
      dst[4] = __float2bfloat16(v1.x); dst[5] = __float2bfloat16(v1.y);
      dst[6] = __float2bfloat16(v1.z); dst[7] = __float2bfloat16(v1.w);
    }
    __syncthreads();

    f32x4 accL[2], accR[2];
#pragma unroll
    for (int c = 0; c < 2; ++c)
#pragma unroll
      for (int r = 0; r < 4; ++r) { accL[c][r] = 0.f; accR[c][r] = 0.f; }

#pragma unroll
    for (int ks = 0; ks < 4; ++ks) {
      const short8 afrag = *(const short8*)&xs[m][ks * 32 + q * 8];
#pragma unroll
      for (int c = 0; c < 2; ++c) {
        accL[c] = __builtin_amdgcn_mfma_f32_16x16x32_bf16(afrag, bfl[c][ks], accL[c], 0, 0, 0);
        accR[c] = __builtin_amdgcn_mfma_f32_16x16x32_bf16(afrag, bfr[c][ks], accR[c], 0, 0, 0);
      }
    }

#pragma unroll
    for (int c = 0; c < 2; ++c) {
      const int n = wave * 32 + c * 16 + m;
#pragma unroll
      for (int r = 0; r < 4; ++r) {
        const size_t row = (size_t)(rowbase + q * 4 + r);
        h[row * D + n] = __float2bfloat16(accL[c][r]);
        out[row * D + n] = accR[c][r] + bias[c];
      }
    }
    __syncthreads();
  }
}

// ---------------------------------------------------------------------------
// scan1: block-level exclusive scan of deg -> offsets + per-block totals.
// ---------------------------------------------------------------------------
__global__ __launch_bounds__(SCAN_BLK) void scan1_kernel(
    const int* __restrict__ deg, int* __restrict__ offsets,
    int* __restrict__ partials, int n) {
  __shared__ int sdata[SCAN_BLK];
  const int t = threadIdx.x;
  const int base = blockIdx.x * SCAN_TILE + t * SCAN_VPT;

  int v[SCAN_VPT];
  int s = 0;
#pragma unroll
  for (int j = 0; j < SCAN_VPT; ++j) {
    v[j] = (base + j < n) ? deg[base + j] : 0;
    s += v[j];
  }
  sdata[t] = s;
  __syncthreads();
  for (int off = 1; off < SCAN_BLK; off <<= 1) {
    int xv = (t >= off) ? sdata[t - off] : 0;
    __syncthreads();
    sdata[t] += xv;
    __syncthreads();
  }
  int excl = sdata[t] - s;
  if (t == SCAN_BLK - 1) partials[blockIdx.x] = sdata[t];
  int run = excl;
#pragma unroll
  for (int j = 0; j < SCAN_VPT; ++j) {
    if (base + j < n) offsets[base + j] = run;
    run += v[j];
  }
}

// ---------------------------------------------------------------------------
// scan3: adds block-prefix (scan2 folded in), materializes pos[] cursors.
// ---------------------------------------------------------------------------
__global__ __launch_bounds__(SCAN_BLK) void scan3_kernel(
    int* __restrict__ offsets, int* __restrict__ pos,
    const int* __restrict__ partials, int n, int n_edges) {
  __shared__ int s_add;
  const int t = threadIdx.x;
  if (t < 64) {
    int v = 0;
    for (int j = t; j < blockIdx.x; j += 64) v += partials[j];
#pragma unroll
    for (int off = 32; off > 0; off >>= 1) v += __shfl_down(v, off);
    if (t == 0) s_add = v;
  }
  __syncthreads();
  const int add = s_add;
  const int base = blockIdx.x * SCAN_TILE + t * SCAN_VPT;
#pragma unroll
  for (int j = 0; j < SCAN_VPT; ++j) {
    const int i = base + j;
    if (i < n) {
      const int o = offsets[i] + add;
      offsets[i] = o;
      pos[i] = o;
    }
  }
  if (blockIdx.x == 0 && t == 0) offsets[n] = n_edges;
}

// ---------------------------------------------------------------------------
// scatter: pairs[slot] = {src, bits(weight)} in dst-sorted order.
// ---------------------------------------------------------------------------
__global__ __launch_bounds__(256) void scatter_kernel(
    const int* __restrict__ esrc, const int* __restrict__ edst,
    const float* __restrict__ ew, int* __restrict__ pos,
    int2* __restrict__ pairs, int n_edges) {
  const int e = blockIdx.x * 256 + threadIdx.x;
  if (e >= n_edges) return;
  const int d = edst[e];
  const int slot = atomicAdd(&pos[d], 1);
  pairs[slot] = make_int2(esrc[e], __float_as_int(ew[e]));
}

// ---------------------------------------------------------------------------
// sage_agg: pure gather-accumulate. One node per wave, no LDS, no barriers.
//   a = out_row (root, precomputed by gemm_hr); single masked 8-deep batch
//   covers the average degree-6 node in ONE latency round (clamped index +
//   zero weight preserves bit-exact accumulation order: fmaf(0,v,a)=a).
// ---------------------------------------------------------------------------
__global__ __launch_bounds__(256) void sage_agg(
    const __hip_bfloat16* __restrict__ h,
    const int* __restrict__ offsets, const int2* __restrict__ pairs,
    float* __restrict__ out, int n_nodes) {
  const int node = blockIdx.x * 4 + (threadIdx.x >> 6);
  const int lane = threadIdx.x & 63;
  if (node >= n_nodes) return;
  const int begin = offsets[node];
  const int end = offsets[node + 1];
  const __hip_bfloat162* __restrict__ h2 = (const __hip_bfloat162*)h;

  float2 a = *(const float2*)&out[(size_t)node * D + 2 * lane];

  int i = begin;
  for (; i + 8 <= end; i += 8) {
    int2 p[8];
#pragma unroll
    for (int u = 0; u < 8; ++u) p[u] = pairs[i + u];
    __hip_bfloat162 hv[8];
#pragma unroll
    for (int u = 0; u < 8; ++u)
      hv[u] = h2[(size_t)p[u].x * (D / 2) + lane];
#pragma unroll
    for (int u = 0; u < 8; ++u) {
      const float w = __int_as_float(p[u].y);
      a.x = fmaf(w, __bfloat162float(hv[u].x), a.x);
      a.y = fmaf(w, __bfloat162float(hv[u].y), a.y);
    }
  }
  if (i < end) {
    int2 p[8];
#pragma unroll
    for (int u = 0; u < 8; ++u) {
      const int ei = (i + u < end) ? (i + u) : (end - 1);   // clamp (valid)
      p[u] = pairs[ei];
      if (i + u >= end) p[u].y = 0;                         // w = 0.0f
    }
    __hip_bfloat162 hv[8];
#pragma unroll
    for (int u = 0; u < 8; ++u)
      hv[u] = h2[(size_t)p[u].x * (D / 2) + lane];
#pragma unroll
    for (int u = 0; u < 8; ++u) {
      const float w = __int_as_float(p[u].y);
      a.x = fmaf(w, __bfloat162float(hv[u].x), a.x);
      a.y = fmaf(w, __bfloat162float(hv[u].y), a.y);
    }
  }

  *(float2*)&out[(size_t)node * D + 2 * lane] = a;
}

// ---------------------------------------------------------------------------
extern "C" void kernel_launch(void* const* d_in, const int* in_sizes, int n_in,
                              void* d_out, int out_size, void* d_ws, size_t ws_size,
                              hipStream_t stream) {
  const float* x   = (const float*)d_in[0];
  const int* esrc  = (const int*)d_in[1];
  const int* edst  = (const int*)d_in[2];
  const float* ew  = (const float*)d_in[3];
  const float* Wl  = (const float*)d_in[4];
  const float* bl  = (const float*)d_in[5];
  const float* Wr  = (const float*)d_in[6];
  const float* br  = (const float*)d_in[7];
  float* out = (float*)d_out;

  const int n_nodes = in_sizes[0] / D;   // 100000
  const int n_edges = in_sizes[1];       // 600000

  // Workspace layout (16B aligned sections)
  char* ws = (char*)d_ws;
  size_t off = 0;
  __hip_bfloat16* h = (__hip_bfloat16*)(ws + off);      // 25.6 MB
  off += (size_t)n_nodes * D * sizeof(__hip_bfloat16);
  off = (off + 15) & ~15ull;
  int* offsets = (int*)(ws + off);
  off += (size_t)(n_nodes + 1) * sizeof(int);
  off = (off + 15) & ~15ull;
  int* pos = (int*)(ws + off);                          // degree, then cursors
  off += (size_t)n_nodes * sizeof(int);
  off = (off + 15) & ~15ull;
  int* partials = (int*)(ws + off);
  off += 1024 * sizeof(int);
  off = (off + 15) & ~15ull;
  int2* pairs = (int2*)(ws + off);                      // 4.8 MB
  off += (size_t)n_edges * sizeof(int2);
  off = (off + 15) & ~15ull;
  __hip_bfloat16* WTl = (__hip_bfloat16*)(ws + off);
  off += (size_t)D * D * sizeof(__hip_bfloat16);
  __hip_bfloat16* WTr = (__hip_bfloat16*)(ws + off);
  off += (size_t)D * D * sizeof(__hip_bfloat16);
  float* bsum = (float*)(ws + off);
  off += D * sizeof(float);

  const int n_rowtiles = (n_nodes + 15) / 16;           // 6250 (exact)

  prep_w<<<128, 256, 0, stream>>>(Wl, Wr, bl, br, WTl, WTr, bsum, pos, n_nodes);

  const int gemm_grid = n_rowtiles < 2048 ? n_rowtiles : 2048;
  gemm_hr<<<gemm_grid, 256, 0, stream>>>(x, WTl, WTr, bsum, h, out, edst, pos,
                                         n_edges, n_rowtiles);

  const int nparts = (n_nodes + SCAN_TILE - 1) / SCAN_TILE;   // 98
  scan1_kernel<<<nparts, SCAN_BLK, 0, stream>>>(pos, offsets, partials, n_nodes);
  scan3_kernel<<<nparts, SCAN_BLK, 0, stream>>>(offsets, pos, partials, n_nodes, n_edges);
  scatter_kernel<<<(n_edges + 255) / 256, 256, 0, stream>>>(esrc, edst, ew, pos, pairs, n_edges);

  sage_agg<<<(n_nodes + 3) / 4, 256, 0, stream>>>(h, offsets, pairs, out, n_nodes);
}